// Round 17
// baseline (533.531 us; speedup 1.0000x reference)
//
#include <hip/hip_runtime.h>

typedef unsigned short u16;
typedef unsigned int   u32;
typedef short  bf16x8 __attribute__((ext_vector_type(8)));
typedef float  f32x4  __attribute__((ext_vector_type(4)));

#define T_SEQ 256
#define BATCH 1024
#define HID   128

__device__ __forceinline__ u16 f2bf(float f) {
  u32 x = __builtin_bit_cast(u32, f);
  x = x + 0x7fffu + ((x >> 16) & 1u);   // round-to-nearest-even
  return (u16)(x >> 16);
}
__device__ __forceinline__ float sigm(float x) {
  return __builtin_amdgcn_rcpf(1.0f + __expf(-x));
}
__device__ __forceinline__ float tanh_f(float x) {
  return 2.0f * __builtin_amdgcn_rcpf(1.0f + __expf(-2.0f * x)) - 1.0f;
}
// R24: producer converts x fp32->bf16 in-register (conv kernel deleted).
// Same f2bf as before -> bit-identical numerics.
__device__ __forceinline__ bf16x8 load_x8(const float* __restrict__ p) {
  float4 a = *(const float4*)(p);
  float4 b = *(const float4*)(p + 4);
  bf16x8 r;
  r[0] = (short)f2bf(a.x); r[1] = (short)f2bf(a.y);
  r[2] = (short)f2bf(a.z); r[3] = (short)f2bf(a.w);
  r[4] = (short)f2bf(b.x); r[5] = (short)f2bf(b.y);
  r[6] = (short)f2bf(b.z); r[7] = (short)f2bf(b.w);
  return r;
}
// LDS-only barrier (R9): hbuf exchange needs lgkmcnt(0) only.
__device__ __forceinline__ void lds_barrier() {
  __builtin_amdgcn_sched_barrier(0);
  asm volatile("s_waitcnt lgkmcnt(0)" ::: "memory");
  __builtin_amdgcn_sched_barrier(0);
  __builtin_amdgcn_s_barrier();
}

// ---------------------------------------------------------------------------
// Prep — R16 TRANSPOSED (gate-major) layout + flag zeroing. conv_x is GONE
// (R24: producer converts in-register). 2048 blocks, single grid-stride pass.
// ---------------------------------------------------------------------------
__global__ void prep_kernel(const float* __restrict__ pre_w, const float* __restrict__ pre_b,
                            const float* __restrict__ w_ih0, const float* __restrict__ w_hh0,
                            const float* __restrict__ b_ih0, const float* __restrict__ b_hh0,
                            const float* __restrict__ w_ih1, const float* __restrict__ w_hh1,
                            const float* __restrict__ b_ih1, const float* __restrict__ b_hh1,
                            u16* __restrict__ WcP, u16* __restrict__ WhhP0,
                            u16* __restrict__ WihP1, u16* __restrict__ WhhP1,
                            float* __restrict__ bias0, float* __restrict__ bias1,
                            u32* __restrict__ flags) {
  if (blockIdx.x == 0 && threadIdx.x < 64) flags[threadIdx.x] = 0;  // 64 u32 = 128 u16
  const int TOT = 230400;
  for (int idx = blockIdx.x * blockDim.x + threadIdx.x; idx < TOT;
       idx += gridDim.x * blockDim.x) {
    if (idx < 32768) {                       // WcP (KK=2)
      int e = idx & 7, lane = (idx >> 3) & 63, kk = (idx >> 9) & 1,
          tile = (idx >> 10) & 1, n = idx >> 11;
      int col = lane & 15, quad = lane >> 4;
      int r = (col & 3) * 128 + n * 8 + tile * 4 + (col >> 2);
      int k = kk * 32 + quad * 8 + e;
      float s = 0.f;
      for (int h = 0; h < 128; ++h)
        s += w_ih0[r * 128 + h] * pre_w[h * 64 + k];
      WcP[idx] = f2bf(s);
    } else if (idx < 33280) {                // bias0 gate-major (fp32)
      int p = idx - 32768;
      int j = p & 3, quad = (p >> 2) & 3, t2 = (p >> 4) & 1, n = p >> 5;
      int r = j * 128 + n * 8 + t2 * 4 + quad;
      float s = b_ih0[r] + b_hh0[r];
      for (int h = 0; h < 128; ++h)
        s += w_ih0[r * 128 + h] * pre_b[h];
      bias0[p] = s;
    } else if (idx < 229888) {               // 3 permuted bf16 copies (KK=4)
      int q = idx - 33280;
      int mat = q / 65536; q = q % 65536;
      int e = q & 7, lane = (q >> 3) & 63, kk = (q >> 9) & 3,
          tile = (q >> 11) & 1, n = q >> 12;
      int col = lane & 15, quad = lane >> 4;
      int r = (col & 3) * 128 + n * 8 + tile * 4 + (col >> 2);
      int k = kk * 32 + quad * 8 + e;
      const float* src = mat == 0 ? w_hh0 : (mat == 1 ? w_ih1 : w_hh1);
      u16* dst = mat == 0 ? WhhP0 : (mat == 1 ? WihP1 : WhhP1);
      dst[q] = f2bf(src[r * 128 + k]);
    } else {                                 // bias1 gate-major (fp32)
      int p = idx - 229888;
      int j = p & 3, quad = (p >> 2) & 3, t2 = (p >> 4) & 1, n = p >> 5;
      int r = j * 128 + n * 8 + t2 * 4 + quad;
      bias1[p] = b_ih1[r] + b_hh1[r];
    }
  }
}

// ---------------------------------------------------------------------------
// R24 SCAN = exact R21/R23 structure (best measured: 314-318 us) with the
// producer reading x_in fp32 DIRECTLY (in-register f2bf; conv kernel gone).
//  * Wave-count curve measured: 16 waves = 510, 8 = 314, 4 = 330. 8 fat
//    waves (512 thr, launch_bounds(512,2) -> 256-reg/wave) is the optimum.
//  * Producer (KKI=2, 24 MFMA/wave/step, VALUBusy 34%) absorbs the 16
//    f2bf/lane/step conversion in measured idle VALU slots.
//  * Consumer path (y0 bf16 via L3 write-through) untouched.
//  * R8 relaxed agent stores/flags, R9 lds_barrier, R13 merged poll,
//    R16 gate-major (no exchange), R17 padded hbuf retained verbatim.
// ---------------------------------------------------------------------------
template <int KKI, bool PROD>
__device__ __forceinline__ void scan_role(
    const float* __restrict__ xf_in, const u16* __restrict__ y0_in,
    const u16* __restrict__ WihF,
    const u16* __restrict__ WhhF, const float* __restrict__ biasP,
    const float* __restrict__ h0_in, const float* __restrict__ c0_in,
    u16* __restrict__ y_out, u16* flag, float* __restrict__ dout,
    const float* __restrict__ post_w, const float* __restrict__ post_b,
    int b0, u32 (*hbuf)[544], float (*h32)[130]) {
  constexpr int KIN = KKI * 32;
  constexpr int LAYER = PROD ? 0 : 1;
  const int tid = threadIdx.x, wave = tid >> 6, lane = tid & 63;  // wave 0..7
  const int col = lane & 15, quad = lane >> 4;
  const int hi = col >> 3;
  const int mrow = col & 7;                        // this lane's batch row (0..7)
  const int jcolA = wave * 16 + hi * 4 + quad;     // cell A h column
  const int jcolB = jcolA + 8;                     // cell B h column

  bf16x8 wih[4][KKI], whh[4][4];
  f32x4 bias4[4];
#pragma unroll
  for (int tau = 0; tau < 4; ++tau) {
    const int g = 4 * wave + tau;                  // global tile index (0..31)
#pragma unroll
    for (int kk = 0; kk < KKI; ++kk)
      wih[tau][kk] = *(const bf16x8*)(WihF + ((g * KKI + kk) * 64 + lane) * 8);
#pragma unroll
    for (int kk = 0; kk < 4; ++kk)
      whh[tau][kk] = *(const bf16x8*)(WhhF + ((g * 4 + kk) * 64 + lane) * 8);
    bias4[tau] = *(const f32x4*)(biasP + g * 16 + quad * 4);
  }

  float cstA = c0_in[(LAYER * BATCH + b0 + mrow) * HID + jcolA];
  float hfA  = h0_in[(LAYER * BATCH + b0 + mrow) * HID + jcolA];
  float cstB = c0_in[(LAYER * BATCH + b0 + mrow) * HID + jcolB];
  float hfB  = h0_in[(LAYER * BATCH + b0 + mrow) * HID + jcolB];

  {  // init hbuf[0] row 'wave' = h0 (linear padded layout) — 8 waves, 8 rows
    const float* src = h0_in + (LAYER * BATCH + b0 + wave) * HID + lane * 2;
    u32 v = (u32)f2bf(src[0]) | ((u32)f2bf(src[1]) << 16);
    hbuf[0][wave * 68 + lane] = v;
  }

  if (!PROD) {  // initial sync: producer must be >= 8 steps ahead (RELAXED poll)
    if (tid == 0) {
      while (__hip_atomic_load(flag, __ATOMIC_RELAXED, __HIP_MEMORY_SCOPE_AGENT) < (u16)8)
        __builtin_amdgcn_s_sleep(4);
    }
  }
  __syncthreads();

  // x source: producer = fp32 x_in (in-register convert); consumer = bf16 y0.
  const float* xfrow = xf_in + (b0 + mrow) * 64;      // producer only
  const u16*   xrow  = y0_in + (b0 + mrow) * KIN;     // consumer only
  bf16x8 ax[KKI], ah[4];
#pragma unroll
  for (int kk = 0; kk < KKI; ++kk) {  // preload x(0)
    if constexpr (PROD) ax[kk] = load_x8(xfrow + kk * 32 + quad * 8);
    else                ax[kk] = *(const bf16x8*)(xrow + kk * 32 + quad * 8);
  }

  for (int t = 0; t < T_SEQ; ++t) {
    const int cb = t & 1, nb = (t + 1) & 1;
#pragma unroll
    for (int kk = 0; kk < 4; ++kk)    // padded row: conflict-free (R17)
      ah[kk] = *(const bf16x8*)((const char*)&hbuf[cb][0] + mrow * 272 +
                                ((kk * 4 + quad) << 4));
    f32x4 acc[4];
#pragma unroll
    for (int tau = 0; tau < 4; ++tau) acc[tau] = bias4[tau];
#pragma unroll
    for (int kk = 0; kk < KKI; ++kk)
#pragma unroll
      for (int tau = 0; tau < 4; ++tau)
        acc[tau] = __builtin_amdgcn_mfma_f32_16x16x32_bf16(wih[tau][kk], ax[kk], acc[tau], 0, 0, 0);
    if (t + 1 < T_SEQ) {   // in-place prefetch x(t+1); flag window covers it
      if constexpr (PROD) {
        const float* xn = xfrow + BATCH * 64;
#pragma unroll
        for (int kk = 0; kk < KKI; ++kk)
          ax[kk] = load_x8(xn + kk * 32 + quad * 8);
      } else {
        const u16* xn = xrow + BATCH * KIN;
#pragma unroll
        for (int kk = 0; kk < KKI; ++kk)
          ax[kk] = *(const bf16x8*)(xn + kk * 32 + quad * 8);
      }
    }
#pragma unroll
    for (int kk = 0; kk < 4; ++kk)
#pragma unroll
      for (int tau = 0; tau < 4; ++tau)
        acc[tau] = __builtin_amdgcn_mfma_f32_16x16x32_bf16(whh[tau][kk], ah[kk], acc[tau], 0, 0, 0);
    // gate phase: two cells per lane, each an exact copy of the R16 pattern.
    {
      float ivA = hi ? acc[1][0] : acc[0][0];
      float fvA = hi ? acc[1][1] : acc[0][1];
      float gvA = hi ? acc[1][2] : acc[0][2];
      float ovA = hi ? acc[1][3] : acc[0][3];
      float siA = sigm(ivA), sfA = sigm(fvA), tgA = tanh_f(gvA), soA = sigm(ovA);
      float cnA = sfA * cstA + siA * tgA;
      cstA = cnA;
      hfA = soA * tanh_f(cnA);
      *(u16*)((char*)&hbuf[nb][0] + mrow * 272 + wave * 32 +
              (hi * 4 + quad) * 2) = f2bf(hfA);
      float ivB = hi ? acc[3][0] : acc[2][0];
      float fvB = hi ? acc[3][1] : acc[2][1];
      float gvB = hi ? acc[3][2] : acc[2][2];
      float ovB = hi ? acc[3][3] : acc[2][3];
      float siB = sigm(ivB), sfB = sigm(fvB), tgB = tanh_f(gvB), soB = sigm(ovB);
      float cnB = sfB * cstB + siB * tgB;
      cstB = cnB;
      hfB = soB * tanh_f(cnB);
      *(u16*)((char*)&hbuf[nb][0] + mrow * 272 + wave * 32 + 16 +
              (hi * 4 + quad) * 2) = f2bf(hfB);
    }
    if (PROD && (t & 3) == 3) {
      __syncthreads();   // full drain: all waves' y0 stores of steps <= t-1 done
      {
        u32 v = hbuf[nb][wave * 68 + lane];
        __hip_atomic_store((u32*)(y_out + (t * BATCH + b0 + wave) * HID + lane * 2), v,
                           __ATOMIC_RELAXED, __HIP_MEMORY_SCOPE_AGENT);
      }
      if (tid == 0)
        __hip_atomic_store(flag, (u16)(t + 1), __ATOMIC_RELAXED, __HIP_MEMORY_SCOPE_AGENT);
    } else {
      // R13: merged consumer poll — fresh load just before the step barrier.
      if (!PROD && (t & 3) == 3 && t + 1 < T_SEQ) {
        if (tid == 0) {
          int nt = t + 9;
          u16 tgt = (u16)(nt > T_SEQ ? T_SEQ : nt);
          while (__hip_atomic_load(flag, __ATOMIC_RELAXED, __HIP_MEMORY_SCOPE_AGENT) < tgt)
            __builtin_amdgcn_s_sleep(4);
        }
      }
      lds_barrier();     // lgkmcnt-only, global ops ride across
      if (PROD) {
        u32 v = hbuf[nb][wave * 68 + lane];
        __hip_atomic_store((u32*)(y_out + (t * BATCH + b0 + wave) * HID + lane * 2), v,
                           __ATOMIC_RELAXED, __HIP_MEMORY_SCOPE_AGENT);
      }
    }
    if constexpr (PROD) xfrow += BATCH * 64;
    else                xrow  += BATCH * KIN;
  }
  if (PROD) {
    __syncthreads();   // drain final y stores
    if (tid == 0)
      __hip_atomic_store(flag, (u16)T_SEQ, __ATOMIC_RELAXED, __HIP_MEMORY_SCOPE_AGENT);
  }

  // ---- finals from fp32 registers (two cells per lane) ----
  dout[BATCH + LAYER * (BATCH * HID) + (b0 + mrow) * HID + jcolA] = hfA;
  dout[BATCH + 2 * BATCH * HID + LAYER * (BATCH * HID) + (b0 + mrow) * HID + jcolA] = cstA;
  dout[BATCH + LAYER * (BATCH * HID) + (b0 + mrow) * HID + jcolB] = hfB;
  dout[BATCH + 2 * BATCH * HID + LAYER * (BATCH * HID) + (b0 + mrow) * HID + jcolB] = cstB;

  if (!PROD) {  // pred via fp32 LDS stage (8 rows, 8 waves)
    h32[mrow][jcolA] = hfA;
    h32[mrow][jcolB] = hfB;
    __syncthreads();
    {
      float a0 = fmaxf(h32[wave][2 * lane], 0.f);
      float a1 = fmaxf(h32[wave][2 * lane + 1], 0.f);
      float p = a0 * post_w[2 * lane] + a1 * post_w[2 * lane + 1];
#pragma unroll
      for (int off = 32; off > 0; off >>= 1) p += __shfl_down(p, off, 64);
      if (lane == 0) dout[b0 + wave] = p + post_b[0];
    }
  }
}

__global__ __launch_bounds__(512, 2) void lstm_fused(
    const float* __restrict__ x_in,
    const u16* __restrict__ WcP, const u16* __restrict__ WhhP0,
    const float* __restrict__ bias0,
    const u16* __restrict__ WihP1, const u16* __restrict__ WhhP1,
    const float* __restrict__ bias1,
    const float* __restrict__ h0_in, const float* __restrict__ c0_in,
    u16* __restrict__ y0, u16* __restrict__ flags, float* __restrict__ dout,
    const float* __restrict__ post_w, const float* __restrict__ post_b) {
  __shared__ __align__(16) u32 hbuf[2][544];
  __shared__ float h32[8][130];
  const int role = blockIdx.x >> 7;      // pairs (L0 b, L1 b) land on same XCD (128%8==0)
  const int blk = blockIdx.x & 127;
  const int b0 = blk * 8;
  if (role == 0)
    scan_role<2, true>(x_in, (const u16*)nullptr, WcP, WhhP0, bias0, h0_in, c0_in,
                       y0, &flags[blk], dout, post_w, post_b, b0, hbuf, h32);
  else
    scan_role<4, false>((const float*)nullptr, y0, WihP1, WhhP1, bias1, h0_in, c0_in,
                        y0, &flags[blk], dout, post_w, post_b, b0, hbuf, h32);
}

extern "C" void kernel_launch(void* const* d_in, const int* in_sizes, int n_in,
                              void* d_out, int out_size, void* d_ws, size_t ws_size,
                              hipStream_t stream) {
  const float* x_in  = (const float*)d_in[0];
  const float* h0    = (const float*)d_in[1];
  const float* c0    = (const float*)d_in[2];
  const float* pre_w = (const float*)d_in[3];
  const float* pre_b = (const float*)d_in[4];
  const float* w_ih0 = (const float*)d_in[5];
  const float* w_hh0 = (const float*)d_in[6];
  const float* b_ih0 = (const float*)d_in[7];
  const float* b_hh0 = (const float*)d_in[8];
  const float* w_ih1 = (const float*)d_in[9];
  const float* w_hh1 = (const float*)d_in[10];
  const float* b_ih1 = (const float*)d_in[11];
  const float* b_hh1 = (const float*)d_in[12];
  const float* post_w = (const float*)d_in[13];
  const float* post_b = (const float*)d_in[14];
  float* out = (float*)d_out;
  char* ws = (char*)d_ws;

  u16*   WcP   = (u16*)(ws + 0);        // 65536 B
  u16*   WhhP0 = (u16*)(ws + 65536);    // 131072 B
  u16*   WihP1 = (u16*)(ws + 196608);   // 131072 B
  u16*   WhhP1 = (u16*)(ws + 327680);   // 131072 B
  float* bias0 = (float*)(ws + 458752); // 2048 B
  float* bias1 = (float*)(ws + 460800); // 2048 B
  u16*   flags = (u16*)(ws + 462848);   // 256 B (128 x u16)
  u16*   y0    = (u16*)(ws + 34017536); // 67108864 B

  prep_kernel<<<dim3(2048), dim3(256), 0, stream>>>(
      pre_w, pre_b, w_ih0, w_hh0, b_ih0, b_hh0, w_ih1, w_hh1, b_ih1, b_hh1,
      WcP, WhhP0, WihP1, WhhP1, bias0, bias1, (u32*)flags);
  lstm_fused<<<dim3(256), dim3(512), 0, stream>>>(
      x_in, WcP, WhhP0, bias0, WihP1, WhhP1, bias1, h0, c0, y0, flags, out,
      post_w, post_b);
}

// Round 18
// 398.304 us; speedup vs baseline: 1.3395x; 1.3395x over previous
//
#include <hip/hip_runtime.h>

typedef unsigned short u16;
typedef unsigned int   u32;
typedef short  bf16x8 __attribute__((ext_vector_type(8)));
typedef float  f32x4  __attribute__((ext_vector_type(4)));

#define T_SEQ 256
#define BATCH 1024
#define HID   128
#define PREP_BLOCKS 2048
#define CONV_BLOCKS 16384

__device__ __forceinline__ u16 f2bf(float f) {
  u32 x = __builtin_bit_cast(u32, f);
  x = x + 0x7fffu + ((x >> 16) & 1u);   // round-to-nearest-even
  return (u16)(x >> 16);
}
__device__ __forceinline__ float sigm(float x) {
  return __builtin_amdgcn_rcpf(1.0f + __expf(-x));
}
__device__ __forceinline__ float tanh_f(float x) {
  return 2.0f * __builtin_amdgcn_rcpf(1.0f + __expf(-2.0f * x)) - 1.0f;
}
// LDS-only barrier (R9): hbuf exchange needs lgkmcnt(0) only.
__device__ __forceinline__ void lds_barrier() {
  __builtin_amdgcn_sched_barrier(0);
  asm volatile("s_waitcnt lgkmcnt(0)" ::: "memory");
  __builtin_amdgcn_sched_barrier(0);
  __builtin_amdgcn_s_barrier();
}

// ---------------------------------------------------------------------------
// R25 = exact R23 (best measured: bench 412.9, scan ~318).
// R24's in-register x conversion REVERTED: the producer is the pacing role;
// doubling its load bytes + 16 f2bf/lane/step slowed the scan 45% (318->462).
// The conv HBM round-trip is cheaper because it runs at full machine
// parallelism OUTSIDE the latency-bound scan loop.
//
// SETUP: conv_x + prep fused into one dispatch (disjoint data; saves a
// launch and overlaps latency-bound prep with BW-bound conv).
// ---------------------------------------------------------------------------
__global__ void setup_kernel(const float* __restrict__ x_in, u16* __restrict__ xb,
                             u32* __restrict__ flags,
                             const float* __restrict__ pre_w, const float* __restrict__ pre_b,
                             const float* __restrict__ w_ih0, const float* __restrict__ w_hh0,
                             const float* __restrict__ b_ih0, const float* __restrict__ b_hh0,
                             const float* __restrict__ w_ih1, const float* __restrict__ w_hh1,
                             const float* __restrict__ b_ih1, const float* __restrict__ b_hh1,
                             u16* __restrict__ WcP, u16* __restrict__ WhhP0,
                             u16* __restrict__ WihP1, u16* __restrict__ WhhP1,
                             float* __restrict__ bias0, float* __restrict__ bias1) {
  const int tid = threadIdx.x;
  if (blockIdx.x < PREP_BLOCKS) {
    if (blockIdx.x == 0 && tid < 64) flags[tid] = 0;  // 64 u32 = 128 u16
    const int TOT = 230400;
    for (int idx = blockIdx.x * 256 + tid; idx < TOT; idx += PREP_BLOCKS * 256) {
      if (idx < 32768) {                       // WcP (KK=2)
        int e = idx & 7, lane = (idx >> 3) & 63, kk = (idx >> 9) & 1,
            tile = (idx >> 10) & 1, n = idx >> 11;
        int col = lane & 15, quad = lane >> 4;
        int r = (col & 3) * 128 + n * 8 + tile * 4 + (col >> 2);
        int k = kk * 32 + quad * 8 + e;
        float s = 0.f;
        for (int h = 0; h < 128; ++h)
          s += w_ih0[r * 128 + h] * pre_w[h * 64 + k];
        WcP[idx] = f2bf(s);
      } else if (idx < 33280) {                // bias0 gate-major (fp32)
        int p = idx - 32768;
        int j = p & 3, quad = (p >> 2) & 3, t2 = (p >> 4) & 1, n = p >> 5;
        int r = j * 128 + n * 8 + t2 * 4 + quad;
        float s = b_ih0[r] + b_hh0[r];
        for (int h = 0; h < 128; ++h)
          s += w_ih0[r * 128 + h] * pre_b[h];
        bias0[p] = s;
      } else if (idx < 229888) {               // 3 permuted bf16 copies (KK=4)
        int q = idx - 33280;
        int mat = q / 65536; q = q % 65536;
        int e = q & 7, lane = (q >> 3) & 63, kk = (q >> 9) & 3,
            tile = (q >> 11) & 1, n = q >> 12;
        int col = lane & 15, quad = lane >> 4;
        int r = (col & 3) * 128 + n * 8 + tile * 4 + (col >> 2);
        int k = kk * 32 + quad * 8 + e;
        const float* src = mat == 0 ? w_hh0 : (mat == 1 ? w_ih1 : w_hh1);
        u16* dst = mat == 0 ? WhhP0 : (mat == 1 ? WihP1 : WhhP1);
        dst[q] = f2bf(src[r * 128 + k]);
      } else {                                 // bias1 gate-major (fp32)
        int p = idx - 229888;
        int j = p & 3, quad = (p >> 2) & 3, t2 = (p >> 4) & 1, n = p >> 5;
        int r = j * 128 + n * 8 + t2 * 4 + quad;
        bias1[p] = b_ih1[r] + b_hh1[r];
      }
    }
  } else {
    // conv part: fp32 -> bf16, 4 elements/thread (verbatim R0 conv_x)
    int i = ((blockIdx.x - PREP_BLOCKS) * 256 + tid) * 4;
    float4 v = *(const float4*)(x_in + i);
    u32 lo = (u32)f2bf(v.x) | ((u32)f2bf(v.y) << 16);
    u32 hi = (u32)f2bf(v.z) | ((u32)f2bf(v.w) << 16);
    *(u32*)(xb + i) = lo;
    *(u32*)(xb + i + 2) = hi;
  }
}

// ---------------------------------------------------------------------------
// SCAN = exact R21 (best measured). Wave-count curve measured: 16 waves = 510,
// 8 = 314, 4 = 330 (1 wave/SIMD loses all TLP). 8 fat waves (512 thr,
// launch_bounds(512,2) -> 256-reg/wave) is the optimum: convoy population
// halved vs 16-wave, weights fit (4 gate-major tiles/wave, VGPR 108, no
// spill), 2 waves/SIMD of latency cover.
//  * Mapping: wave owns 16 jcols, tiles g = 4*wave+tau; cellA
//    (jcol = wave*16+hi*4+quad) from tiles 0/1, cellB (jcolA+8) from 2/3.
//  * R8 relaxed agent stores/flags, R9 lds_barrier, R13 merged poll,
//    R16 gate-major (no exchange), R17 padded hbuf retained verbatim.
// ---------------------------------------------------------------------------
template <int KKI, bool PROD>
__device__ __forceinline__ void scan_role(
    const u16* __restrict__ xsrc, const u16* __restrict__ WihF,
    const u16* __restrict__ WhhF, const float* __restrict__ biasP,
    const float* __restrict__ h0_in, const float* __restrict__ c0_in,
    u16* __restrict__ y_out, u16* flag, float* __restrict__ dout,
    const float* __restrict__ post_w, const float* __restrict__ post_b,
    int b0, u32 (*hbuf)[544], float (*h32)[130]) {
  constexpr int KIN = KKI * 32;
  constexpr int LAYER = PROD ? 0 : 1;
  const int tid = threadIdx.x, wave = tid >> 6, lane = tid & 63;  // wave 0..7
  const int col = lane & 15, quad = lane >> 4;
  const int hi = col >> 3;
  const int mrow = col & 7;                        // this lane's batch row (0..7)
  const int jcolA = wave * 16 + hi * 4 + quad;     // cell A h column
  const int jcolB = jcolA + 8;                     // cell B h column

  bf16x8 wih[4][KKI], whh[4][4];
  f32x4 bias4[4];
#pragma unroll
  for (int tau = 0; tau < 4; ++tau) {
    const int g = 4 * wave + tau;                  // global tile index (0..31)
#pragma unroll
    for (int kk = 0; kk < KKI; ++kk)
      wih[tau][kk] = *(const bf16x8*)(WihF + ((g * KKI + kk) * 64 + lane) * 8);
#pragma unroll
    for (int kk = 0; kk < 4; ++kk)
      whh[tau][kk] = *(const bf16x8*)(WhhF + ((g * 4 + kk) * 64 + lane) * 8);
    bias4[tau] = *(const f32x4*)(biasP + g * 16 + quad * 4);
  }

  float cstA = c0_in[(LAYER * BATCH + b0 + mrow) * HID + jcolA];
  float hfA  = h0_in[(LAYER * BATCH + b0 + mrow) * HID + jcolA];
  float cstB = c0_in[(LAYER * BATCH + b0 + mrow) * HID + jcolB];
  float hfB  = h0_in[(LAYER * BATCH + b0 + mrow) * HID + jcolB];

  {  // init hbuf[0] row 'wave' = h0 (linear padded layout) — 8 waves, 8 rows
    const float* src = h0_in + (LAYER * BATCH + b0 + wave) * HID + lane * 2;
    u32 v = (u32)f2bf(src[0]) | ((u32)f2bf(src[1]) << 16);
    hbuf[0][wave * 68 + lane] = v;
  }

  if (!PROD) {  // initial sync: producer must be >= 8 steps ahead (RELAXED poll)
    if (tid == 0) {
      while (__hip_atomic_load(flag, __ATOMIC_RELAXED, __HIP_MEMORY_SCOPE_AGENT) < (u16)8)
        __builtin_amdgcn_s_sleep(4);
    }
  }
  __syncthreads();

  const u16* xrow = xsrc + (b0 + mrow) * KIN;  // lanes l, l^8 same row (dup B cols)
  bf16x8 ax[KKI], ah[4];
#pragma unroll
  for (int kk = 0; kk < KKI; ++kk)   // preload x(0)
    ax[kk] = *(const bf16x8*)(xrow + kk * 32 + quad * 8);

  for (int t = 0; t < T_SEQ; ++t) {
    const int cb = t & 1, nb = (t + 1) & 1;
#pragma unroll
    for (int kk = 0; kk < 4; ++kk)    // padded row: conflict-free (R17)
      ah[kk] = *(const bf16x8*)((const char*)&hbuf[cb][0] + mrow * 272 +
                                ((kk * 4 + quad) << 4));
    f32x4 acc[4];
#pragma unroll
    for (int tau = 0; tau < 4; ++tau) acc[tau] = bias4[tau];
#pragma unroll
    for (int kk = 0; kk < KKI; ++kk)
#pragma unroll
      for (int tau = 0; tau < 4; ++tau)
        acc[tau] = __builtin_amdgcn_mfma_f32_16x16x32_bf16(wih[tau][kk], ax[kk], acc[tau], 0, 0, 0);
    if (t + 1 < T_SEQ) {   // in-place prefetch x(t+1); flag window covers it
      const u16* xn = xrow + BATCH * KIN;
#pragma unroll
      for (int kk = 0; kk < KKI; ++kk)
        ax[kk] = *(const bf16x8*)(xn + kk * 32 + quad * 8);
    }
#pragma unroll
    for (int kk = 0; kk < 4; ++kk)
#pragma unroll
      for (int tau = 0; tau < 4; ++tau)
        acc[tau] = __builtin_amdgcn_mfma_f32_16x16x32_bf16(whh[tau][kk], ah[kk], acc[tau], 0, 0, 0);
    // gate phase: two cells per lane, each an exact copy of the R16 pattern.
    {
      float ivA = hi ? acc[1][0] : acc[0][0];
      float fvA = hi ? acc[1][1] : acc[0][1];
      float gvA = hi ? acc[1][2] : acc[0][2];
      float ovA = hi ? acc[1][3] : acc[0][3];
      float siA = sigm(ivA), sfA = sigm(fvA), tgA = tanh_f(gvA), soA = sigm(ovA);
      float cnA = sfA * cstA + siA * tgA;
      cstA = cnA;
      hfA = soA * tanh_f(cnA);
      *(u16*)((char*)&hbuf[nb][0] + mrow * 272 + wave * 32 +
              (hi * 4 + quad) * 2) = f2bf(hfA);
      float ivB = hi ? acc[3][0] : acc[2][0];
      float fvB = hi ? acc[3][1] : acc[2][1];
      float gvB = hi ? acc[3][2] : acc[2][2];
      float ovB = hi ? acc[3][3] : acc[2][3];
      float siB = sigm(ivB), sfB = sigm(fvB), tgB = tanh_f(gvB), soB = sigm(ovB);
      float cnB = sfB * cstB + siB * tgB;
      cstB = cnB;
      hfB = soB * tanh_f(cnB);
      *(u16*)((char*)&hbuf[nb][0] + mrow * 272 + wave * 32 + 16 +
              (hi * 4 + quad) * 2) = f2bf(hfB);
    }
    if (PROD && (t & 3) == 3) {
      __syncthreads();   // full drain: all waves' y0 stores of steps <= t-1 done
      {
        u32 v = hbuf[nb][wave * 68 + lane];
        __hip_atomic_store((u32*)(y_out + (t * BATCH + b0 + wave) * HID + lane * 2), v,
                           __ATOMIC_RELAXED, __HIP_MEMORY_SCOPE_AGENT);
      }
      if (tid == 0)
        __hip_atomic_store(flag, (u16)(t + 1), __ATOMIC_RELAXED, __HIP_MEMORY_SCOPE_AGENT);
    } else {
      // R13: merged consumer poll — fresh load just before the step barrier.
      if (!PROD && (t & 3) == 3 && t + 1 < T_SEQ) {
        if (tid == 0) {
          int nt = t + 9;
          u16 tgt = (u16)(nt > T_SEQ ? T_SEQ : nt);
          while (__hip_atomic_load(flag, __ATOMIC_RELAXED, __HIP_MEMORY_SCOPE_AGENT) < tgt)
            __builtin_amdgcn_s_sleep(4);
        }
      }
      lds_barrier();     // lgkmcnt-only, global ops ride across
      if (PROD) {
        u32 v = hbuf[nb][wave * 68 + lane];
        __hip_atomic_store((u32*)(y_out + (t * BATCH + b0 + wave) * HID + lane * 2), v,
                           __ATOMIC_RELAXED, __HIP_MEMORY_SCOPE_AGENT);
      }
    }
    xrow += BATCH * KIN;
  }
  if (PROD) {
    __syncthreads();   // drain final y stores
    if (tid == 0)
      __hip_atomic_store(flag, (u16)T_SEQ, __ATOMIC_RELAXED, __HIP_MEMORY_SCOPE_AGENT);
  }

  // ---- finals from fp32 registers (two cells per lane) ----
  dout[BATCH + LAYER * (BATCH * HID) + (b0 + mrow) * HID + jcolA] = hfA;
  dout[BATCH + 2 * BATCH * HID + LAYER * (BATCH * HID) + (b0 + mrow) * HID + jcolA] = cstA;
  dout[BATCH + LAYER * (BATCH * HID) + (b0 + mrow) * HID + jcolB] = hfB;
  dout[BATCH + 2 * BATCH * HID + LAYER * (BATCH * HID) + (b0 + mrow) * HID + jcolB] = cstB;

  if (!PROD) {  // pred via fp32 LDS stage (8 rows, 8 waves)
    h32[mrow][jcolA] = hfA;
    h32[mrow][jcolB] = hfB;
    __syncthreads();
    {
      float a0 = fmaxf(h32[wave][2 * lane], 0.f);
      float a1 = fmaxf(h32[wave][2 * lane + 1], 0.f);
      float p = a0 * post_w[2 * lane] + a1 * post_w[2 * lane + 1];
#pragma unroll
      for (int off = 32; off > 0; off >>= 1) p += __shfl_down(p, off, 64);
      if (lane == 0) dout[b0 + wave] = p + post_b[0];
    }
  }
}

__global__ __launch_bounds__(512, 2) void lstm_fused(
    const u16* __restrict__ xb,
    const u16* __restrict__ WcP, const u16* __restrict__ WhhP0,
    const float* __restrict__ bias0,
    const u16* __restrict__ WihP1, const u16* __restrict__ WhhP1,
    const float* __restrict__ bias1,
    const float* __restrict__ h0_in, const float* __restrict__ c0_in,
    u16* __restrict__ y0, u16* __restrict__ flags, float* __restrict__ dout,
    const float* __restrict__ post_w, const float* __restrict__ post_b) {
  __shared__ __align__(16) u32 hbuf[2][544];
  __shared__ float h32[8][130];
  const int role = blockIdx.x >> 7;      // pairs (L0 b, L1 b) land on same XCD (128%8==0)
  const int blk = blockIdx.x & 127;
  const int b0 = blk * 8;
  if (role == 0)
    scan_role<2, true>(xb, WcP, WhhP0, bias0, h0_in, c0_in, y0, &flags[blk], dout,
                       post_w, post_b, b0, hbuf, h32);
  else
    scan_role<4, false>(y0, WihP1, WhhP1, bias1, h0_in, c0_in, y0, &flags[blk], dout,
                        post_w, post_b, b0, hbuf, h32);
}

extern "C" void kernel_launch(void* const* d_in, const int* in_sizes, int n_in,
                              void* d_out, int out_size, void* d_ws, size_t ws_size,
                              hipStream_t stream) {
  const float* x_in  = (const float*)d_in[0];
  const float* h0    = (const float*)d_in[1];
  const float* c0    = (const float*)d_in[2];
  const float* pre_w = (const float*)d_in[3];
  const float* pre_b = (const float*)d_in[4];
  const float* w_ih0 = (const float*)d_in[5];
  const float* w_hh0 = (const float*)d_in[6];
  const float* b_ih0 = (const float*)d_in[7];
  const float* b_hh0 = (const float*)d_in[8];
  const float* w_ih1 = (const float*)d_in[9];
  const float* w_hh1 = (const float*)d_in[10];
  const float* b_ih1 = (const float*)d_in[11];
  const float* b_hh1 = (const float*)d_in[12];
  const float* post_w = (const float*)d_in[13];
  const float* post_b = (const float*)d_in[14];
  float* out = (float*)d_out;
  char* ws = (char*)d_ws;

  u16*   WcP   = (u16*)(ws + 0);        // 65536 B
  u16*   WhhP0 = (u16*)(ws + 65536);    // 131072 B
  u16*   WihP1 = (u16*)(ws + 196608);   // 131072 B
  u16*   WhhP1 = (u16*)(ws + 327680);   // 131072 B
  float* bias0 = (float*)(ws + 458752); // 2048 B
  float* bias1 = (float*)(ws + 460800); // 2048 B
  u16*   flags = (u16*)(ws + 462848);   // 256 B (128 x u16)
  u16*   xb    = (u16*)(ws + 463104);   // 33554432 B
  u16*   y0    = (u16*)(ws + 34017536); // 67108864 B

  setup_kernel<<<dim3(PREP_BLOCKS + CONV_BLOCKS), dim3(256), 0, stream>>>(
      x_in, xb, (u32*)flags, pre_w, pre_b, w_ih0, w_hh0, b_ih0, b_hh0,
      w_ih1, w_hh1, b_ih1, b_hh1, WcP, WhhP0, WihP1, WhhP1, bias0, bias1);
  lstm_fused<<<dim3(256), dim3(512), 0, stream>>>(
      xb, WcP, WhhP0, bias0, WihP1, WhhP1, bias1, h0, c0, y0, flags, out,
      post_w, post_b);
}